// Round 6
// baseline (488.411 us; speedup 1.0000x reference)
//
#include <hip/hip_runtime.h>
#include <stdint.h>

// DyDCNv2 + GroupNorm(16). B=8, C=O=256, H=W=64, fp32 in/out.
// Implicit GEMM M=32768,N=256,K=2304 bf16 MFMA.
// R6: K-split x2 (grid 1024, 4 blocks/CU = 16 waves/CU) with partial-sum
// buffer + fused reduce in k_gn; interp VALU cut ~3x (free bfhi reinterpret,
// v_perm_b32 bf16 pack). Step structure identical to R5 (64ch steps,
// lgkm-only barriers, register weight dbuf). Runtime ws_size fallback.

#define B_ 8
#define C_ 256
#define O_ 256
#define H_ 64
#define W_ 64
#define HW_ 4096
#define KTOT 2304
#define GROUPS_ 16
#define EPS_ 1e-5f
#define NSTEP 36           // total K steps (64 ch each)
#define VROW 72            // lds_v row stride in u16 (64 data + 8 pad)

typedef float  f32x4  __attribute__((ext_vector_type(4)));
typedef short  short8 __attribute__((ext_vector_type(8)));
typedef unsigned int   u32;
typedef unsigned short u16;

// workspace layout (bytes)
#define XT_BYTES   (B_*HW_*C_*2)                // 16,777,216  xt [B][HW][C] bf16
#define WIMG_OFF   XT_BYTES
#define WIMG_BYTES (72*16*64*16)                // 1,179,648  frag-packed bf16 weights
#define STATS_OFF  (WIMG_OFF + WIMG_BYTES)      // 256 floats
#define PART_OFF   (STATS_OFF + 1024)           // 33,554,432  K-split partial (f32)
#define WS_NEED    (PART_OFF + (size_t)B_*O_*HW_*4)

__device__ __forceinline__ u32 bf16r(float f) {  // RNE f32->bf16
    u32 u = __float_as_uint(f);
    return (u + 0x7fffu + ((u >> 16) & 1u)) >> 16;
}
__device__ __forceinline__ u32 pack_bf16x2(float lo, float hi) {
    return bf16r(lo) | (bf16r(hi) << 16);
}
// 1-op pack: D = [hi.b3 hi.b2 lo.b3 lo.b2] (truncation round; errors cancel over K)
__device__ __forceinline__ u32 pack_perm(float lo, float hi) {
    return __builtin_amdgcn_perm(__float_as_uint(hi), __float_as_uint(lo), 0x07060302u);
}
__device__ __forceinline__ float bflo(u32 u) { return __uint_as_float(u << 16); }
// free: high bf16 in place; low 16 bits are the other bf16 (rel err < 2^-8, in budget)
__device__ __forceinline__ float bfhi_f(u32 u) { return __uint_as_float(u); }

// barrier waiting only on LDS ops: register-destined global loads stay in flight
__device__ __forceinline__ void barrier_lds() {
    asm volatile("s_waitcnt lgkmcnt(0)\n\ts_barrier" ::: "memory");
}

// ---------------------------------------------------------------- prep: transpose + packw
__global__ void k_prep(const float* __restrict__ x, u16* __restrict__ xt,
                       const float* __restrict__ w, u16* __restrict__ wimg) {
    const int bid = blockIdx.x;
    const int tid = threadIdx.x;
    if (bid < 2048) {
        // transpose x[B][C][HW] -> xt[B][HW][C] bf16, 64c x 64p tiles
        __shared__ float tile[64][65];
        const int b = bid >> 8, ct = (bid >> 6) & 3, pt = bid & 63;
#pragma unroll
        for (int pass = 0; pass < 4; ++pass) {
            const int r  = (tid >> 4) + pass * 16;
            const int pq = tid & 15;
            const f32x4 v = *(const f32x4*)&x[(((size_t)(b * C_ + ct * 64 + r)) << 12)
                                              + pt * 64 + pq * 4];
            tile[r][pq * 4 + 0] = v.x;
            tile[r][pq * 4 + 1] = v.y;
            tile[r][pq * 4 + 2] = v.z;
            tile[r][pq * 4 + 3] = v.w;
        }
        __syncthreads();
        const int pr = tid >> 2, cg = tid & 3;    // 64 p-rows x 4 groups of 16 ch
        u32 o[8];
#pragma unroll
        for (int j = 0; j < 8; ++j)
            o[j] = pack_bf16x2(tile[cg * 16 + 2 * j][pr], tile[cg * 16 + 2 * j + 1][pr]);
        u16* dst = &xt[(((size_t)b << 12) + pt * 64 + pr) * 256 + ct * 64 + cg * 16];
        *(uint4*)dst       = *(uint4*)&o[0];
        *(uint4*)(dst + 8) = *(uint4*)&o[4];
    } else {
        // pack weights: wimg[sub][frag][lane][8], sub = k*8+ctile;
        // lane(col,quad) holds W[n=frag*16+col][c0+quad*8+j][k]
        const int sub = bid - 2048;       // 0..71
        const int k  = sub >> 3;
        const int c0 = (sub & 7) * 32;
#pragma unroll
        for (int i = 0; i < 4; ++i) {
            const int item = tid + i * 256;    // frag*64 + lane
            const int lane = item & 63;
            const int frag = item >> 6;
            const int col = lane & 15, quad = lane >> 4;
            const int n = frag * 16 + col;
            const float* src = w + (size_t)n * KTOT + (size_t)(c0 + quad * 8) * 9 + k;
            u32 o[4];
#pragma unroll
            for (int j = 0; j < 4; ++j)
                o[j] = pack_bf16x2(src[(size_t)(2 * j) * 9], src[(size_t)(2 * j + 1) * 9]);
            *(uint4*)&wimg[((size_t)sub * 1024 + item) * 8] = *(uint4*)o;
        }
    }
}

// ---------------------------------------------------------------- k_dcn helpers
__device__ __forceinline__ void issue_gather(const u16* __restrict__ cb,
                                             const float* __restrict__ mwp,
                                             const int* __restrict__ mip,
                                             int gpos, uint4 g[8], f32x4& mw) {
    mw = *(const f32x4*)&mwp[gpos * 4];
    const int4 ix = *(const int4*)&mip[gpos * 4];
    const u16* p0 = cb + ix.x;
    const u16* p1 = cb + ix.y;
    const u16* p2 = cb + ix.z;
    const u16* p3 = cb + ix.w;
    g[0] = *(const uint4*)p0; g[1] = *(const uint4*)(p0 + 8);
    g[2] = *(const uint4*)p1; g[3] = *(const uint4*)(p1 + 8);
    g[4] = *(const uint4*)p2; g[5] = *(const uint4*)(p2 + 8);
    g[6] = *(const uint4*)p3; g[7] = *(const uint4*)(p3 + 8);
}

__device__ __forceinline__ void interp_store(const uint4 g[8], f32x4 mw, u16* dst) {
    float s[16];
#pragma unroll
    for (int i = 0; i < 16; ++i) s[i] = 0.f;
    const float ww[4] = {mw.x, mw.y, mw.z, mw.w};
#pragma unroll
    for (int cr = 0; cr < 4; ++cr) {
        const float wg = ww[cr];
        const uint4 a = g[2 * cr], bq = g[2 * cr + 1];
        s[0]  += wg * bflo(a.x);  s[1]  += wg * bfhi_f(a.x);
        s[2]  += wg * bflo(a.y);  s[3]  += wg * bfhi_f(a.y);
        s[4]  += wg * bflo(a.z);  s[5]  += wg * bfhi_f(a.z);
        s[6]  += wg * bflo(a.w);  s[7]  += wg * bfhi_f(a.w);
        s[8]  += wg * bflo(bq.x); s[9]  += wg * bfhi_f(bq.x);
        s[10] += wg * bflo(bq.y); s[11] += wg * bfhi_f(bq.y);
        s[12] += wg * bflo(bq.z); s[13] += wg * bfhi_f(bq.z);
        s[14] += wg * bflo(bq.w); s[15] += wg * bfhi_f(bq.w);
    }
    uint4 pk0, pk1;
    pk0.x = pack_perm(s[0], s[1]);   pk0.y = pack_perm(s[2], s[3]);
    pk0.z = pack_perm(s[4], s[5]);   pk0.w = pack_perm(s[6], s[7]);
    pk1.x = pack_perm(s[8], s[9]);   pk1.y = pack_perm(s[10], s[11]);
    pk1.z = pack_perm(s[12], s[13]); pk1.w = pack_perm(s[14], s[15]);
    *(uint4*)dst = pk0;
    *(uint4*)(dst + 8) = pk1;
}

__device__ __forceinline__ void load_wfrags(const u16* __restrict__ wimg, int s,
                                            int wid, int lane, short8 bf[8]) {
#pragma unroll
    for (int kc = 0; kc < 2; ++kc)
#pragma unroll
        for (int ni = 0; ni < 4; ++ni)
            bf[kc * 4 + ni] = *(const short8*)
                &wimg[(((size_t)(2 * s + kc) * 16 + wid * 4 + ni) * 64 + lane) * 8];
}

// ---------------------------------------------------------------- main fused DCN GEMM
// grid = 8 * 64 * nhalves. b = gid&7 (XCD-affine), m-tile = (gid>>3)&63,
// half = gid>>9 covers K steps [half*half_len, +half_len).
// 256 thr = 4 waves; wave w: 64 pos x n in [w*64, +64). Step = 64 channels.
__launch_bounds__(256, 4)
__global__ void k_dcn(const u16* __restrict__ xt, const u16* __restrict__ wimg,
                      const float* __restrict__ offp, const float* __restrict__ mskp,
                      float* __restrict__ out0, float* __restrict__ out1,
                      float* __restrict__ stats, int half_len) {
    __shared__ __align__(16) float meta_w[9 * 64 * 4];   // 9216 B
    __shared__ __align__(16) int   meta_i[9 * 64 * 4];   // 9216 B
    __shared__ __align__(16) u16   lds_v[2][64 * VROW];  // 18432 B dbuf val tile

    const int tid = threadIdx.x;
    const int gid = blockIdx.x;
    const int b   = gid & 7;            // XCD-affine
    const int m0  = ((gid >> 3) & 63) * 64;
    const int half = gid >> 9;
    const int s0 = half * half_len, s1 = s0 + half_len;
    const int klo = s0 >> 2;
    const int kcnt = ((s1 - 1) >> 2) - klo + 1;
    float* outbuf = half ? out1 : out0;

    const int lane = tid & 63, wid = tid >> 6;
    const int col = lane & 15, quad = lane >> 4;
    const int gpos = tid >> 2, oct = tid & 3;   // gather role: (pos 0..63, 16-ch oct)

    const u16* xtb = xt + ((size_t)b << 20);

    // ---- bilinear meta for 64 positions x kcnt kernel points
    for (int it = tid; it < 64 * kcnt; it += 256) {
        const int pos = it & 63, k = klo + (it >> 6);
        const int pg = m0 + pos;
        const int hh = pg >> 6, wwi = pg & 63;
        const float dy = offp[((size_t)(b * 18 + 2 * k) << 12) + pg];
        const float dx = offp[((size_t)(b * 18 + 2 * k + 1) << 12) + pg];
        const float mv = mskp[((size_t)(b * 9 + k) << 12) + pg];
        const float ys = (float)(hh + (k / 3) - 1) + dy;
        const float xs = (float)(wwi + (k % 3) - 1) + dx;
        const float y0f = floorf(ys), x0f = floorf(xs);
        const int y0 = (int)y0f, x0 = (int)x0f;
        const float wy1 = ys - y0f, wx1 = xs - x0f;
        const float wy0 = 1.f - wy1, wx0 = 1.f - wx1;
        const int y1 = y0 + 1, x1 = x0 + 1;
        const float vy0 = (y0 >= 0 && y0 < H_) ? 1.f : 0.f;
        const float vy1 = (y1 >= 0 && y1 < H_) ? 1.f : 0.f;
        const float vx0 = (x0 >= 0 && x0 < W_) ? 1.f : 0.f;
        const float vx1 = (x1 >= 0 && x1 < W_) ? 1.f : 0.f;
        const int y0c = min(max(y0, 0), H_ - 1), y1c = min(max(y1, 0), H_ - 1);
        const int x0c = min(max(x0, 0), W_ - 1), x1c = min(max(x1, 0), W_ - 1);
        meta_w[it * 4 + 0] = mv * wy0 * wx0 * vy0 * vx0;
        meta_w[it * 4 + 1] = mv * wy0 * wx1 * vy0 * vx1;
        meta_w[it * 4 + 2] = mv * wy1 * wx0 * vy1 * vx0;
        meta_w[it * 4 + 3] = mv * wy1 * wx1 * vy1 * vx1;
        meta_i[it * 4 + 0] = (y0c * W_ + x0c) << 8;   // row offsets in u16 units
        meta_i[it * 4 + 1] = (y0c * W_ + x1c) << 8;
        meta_i[it * 4 + 2] = (y1c * W_ + x0c) << 8;
        meta_i[it * 4 + 3] = (y1c * W_ + x1c) << 8;
    }
    __syncthreads();

    // ---- prologue: stage step s0 into lds_v[0]; load weight frags for s0
    uint4 g[8]; f32x4 mw; short8 bf_cur[8], bf_nxt[8];
    {
        const int kn = s0 >> 2, c0 = (s0 & 3) * 64;
        issue_gather(xtb + c0 + oct * 16, &meta_w[(kn - klo) * 256],
                     &meta_i[(kn - klo) * 256], gpos, g, mw);
    }
    load_wfrags(wimg, s0, wid, lane, bf_cur);
    interp_store(g, mw, &lds_v[0][gpos * VROW + oct * 16]);
    __syncthreads();

    f32x4 acc[4][4];
#pragma unroll
    for (int i = 0; i < 4; ++i)
#pragma unroll
        for (int j = 0; j < 4; ++j) acc[i][j] = (f32x4){0.f, 0.f, 0.f, 0.f};

#pragma unroll 2
    for (int i = 0; i < half_len; ++i) {
        const int s = s0 + i;
        const int p = i & 1;
        const bool pf = (i + 1 < half_len);

        // 1. weight frags for s+1 (distance-1 register prefetch)
        if (pf) load_wfrags(wimg, s + 1, wid, lane, bf_nxt);

        // 2. gathers for s+1 (consumed at bottom of this step)
        if (pf) {
            const int sn = s + 1;
            const int kn = sn >> 2, c0n = (sn & 3) * 64;
            issue_gather(xtb + c0n + oct * 16, &meta_w[(kn - klo) * 256],
                         &meta_i[(kn - klo) * 256], gpos, g, mw);
        }

        // 3. compute current step: 2 sub-steps of 32 ch
#pragma unroll
        for (int kc = 0; kc < 2; ++kc) {
            short8 af[4];
#pragma unroll
            for (int mi = 0; mi < 4; ++mi)
                af[mi] = *(const short8*)
                    &lds_v[p][(mi * 16 + col) * VROW + kc * 32 + quad * 8];
#pragma unroll
            for (int mi = 0; mi < 4; ++mi)
#pragma unroll
                for (int ni = 0; ni < 4; ++ni)
                    acc[mi][ni] = __builtin_amdgcn_mfma_f32_16x16x32_bf16(
                        af[mi], bf_cur[kc * 4 + ni], acc[mi][ni], 0, 0, 0);
        }

        // 4. interp s+1 into the other buffer
        if (pf) interp_store(g, mw, &lds_v[1 - p][gpos * VROW + oct * 16]);

        // 5. LDS-only barrier: weight/gather prefetches stay in flight
        barrier_lds();

#pragma unroll
        for (int j = 0; j < 8; ++j) bf_cur[j] = bf_nxt[j];
    }

    // ---- epilogue: store partial output. D: row(pos)=quad*4+r, col(o)=lane&15.
#pragma unroll
    for (int mi = 0; mi < 4; ++mi)
#pragma unroll
        for (int ni = 0; ni < 4; ++ni) {
            const int o  = wid * 64 + ni * 16 + col;
            const int pg = m0 + mi * 16 + quad * 4;
            *(f32x4*)(outbuf + (((size_t)b * O_ + o) << 12) + pg) = acc[mi][ni];
        }

    // ---- GN stats (linear in partials): (wave, ni) = one 16-ch group x 64 pos
#pragma unroll
    for (int ni = 0; ni < 4; ++ni) {
        float s = 0.f, s2 = 0.f;
#pragma unroll
        for (int mi = 0; mi < 4; ++mi) {
            f32x4 v = acc[mi][ni];
            s  += v.x + v.y + v.z + v.w;
        }
#pragma unroll
        for (int d = 32; d > 0; d >>= 1) s += __shfl_xor(s, d, 64);
        if (lane == 0) {
            const int gI = wid * 4 + ni;
            atomicAdd(&stats[b * GROUPS_ + gI], s);
        }
        (void)s2;
    }
}

// ---------------------------------------------------------------- GN apply (K-split: sum partials)
// sum-of-squares must come from the SUMMED output, so compute sumsq here per
// (b,o) row, reduce into stats2, then a tiny second pass normalizes.
__global__ void k_sumsq(const float* __restrict__ out0, const float* __restrict__ out1,
                        float* __restrict__ outsum, float* __restrict__ stats) {
    const int blk = blockIdx.x;            // b*256 + o
    const int b = blk >> 8, o = blk & 255;
    const int t = threadIdx.x;
    const f32x4* p0 = (const f32x4*)(out0 + ((size_t)blk << 12));
    const f32x4* p1 = (const f32x4*)(out1 + ((size_t)blk << 12));
    f32x4* po = (f32x4*)(outsum + ((size_t)blk << 12));
    float s2 = 0.f;
#pragma unroll
    for (int i = 0; i < 4; ++i) {
        f32x4 v = p0[t + i * 256] + p1[t + i * 256];
        po[t + i * 256] = v;
        s2 += v.x * v.x + v.y * v.y + v.z * v.z + v.w * v.w;
    }
#pragma unroll
    for (int d = 32; d > 0; d >>= 1) s2 += __shfl_xor(s2, d, 64);
    __shared__ float red[4];
    if ((t & 63) == 0) red[t >> 6] = s2;
    __syncthreads();
    if (t == 0)
        atomicAdd(&stats[128 + b * GROUPS_ + (o >> 4)],
                  red[0] + red[1] + red[2] + red[3]);
}

// single-pass variant (no K-split): sumsq from acc was dropped, compute here too
__global__ void k_sumsq1(const float* __restrict__ out0, float* __restrict__ stats) {
    const int blk = blockIdx.x;
    const int b = blk >> 8, o = blk & 255;
    const int t = threadIdx.x;
    const f32x4* p0 = (const f32x4*)(out0 + ((size_t)blk << 12));
    float s2 = 0.f;
#pragma unroll
    for (int i = 0; i < 4; ++i) {
        f32x4 v = p0[t + i * 256];
        s2 += v.x * v.x + v.y * v.y + v.z * v.z + v.w * v.w;
    }
#pragma unroll
    for (int d = 32; d > 0; d >>= 1) s2 += __shfl_xor(s2, d, 64);
    __shared__ float red[4];
    if ((t & 63) == 0) red[t >> 6] = s2;
    __syncthreads();
    if (t == 0)
        atomicAdd(&stats[128 + b * GROUPS_ + (o >> 4)],
                  red[0] + red[1] + red[2] + red[3]);
}

// ---------------------------------------------------------------- apply GN in place
__global__ void k_gn(float* __restrict__ out, const float* __restrict__ stats,
                     const float* __restrict__ gamma, const float* __restrict__ beta) {
    const int blk = blockIdx.x;            // b*256 + o
    const int b = blk >> 8, o = blk & 255;
    const int gI = b * GROUPS_ + (o >> 4);
    const float n = 65536.f;               // (C/G)*H*W
    const float mean = stats[gI] / n;
    const float var  = stats[128 + gI] / n - mean * mean;
    const float inv  = rsqrtf(fmaxf(var, 0.f) + EPS_);
    const float scale = inv * gamma[o];
    const float shift = beta[o] - mean * scale;
    f32x4* p = (f32x4*)(out + ((size_t)blk << 12));
    const int t = threadIdx.x;
#pragma unroll
    for (int i = 0; i < 4; ++i) {
        f32x4 v = p[t + i * 256];
        p[t + i * 256] = v * scale + shift;
    }
}

extern "C" void kernel_launch(void* const* d_in, const int* in_sizes, int n_in,
                              void* d_out, int out_size, void* d_ws, size_t ws_size,
                              hipStream_t stream) {
    const float* x     = (const float*)d_in[0];
    const float* offp  = (const float*)d_in[1];
    const float* mskp  = (const float*)d_in[2];
    const float* w     = (const float*)d_in[3];
    const float* gamma = (const float*)d_in[4];
    const float* beta  = (const float*)d_in[5];
    float* outp = (float*)d_out;

    u16*   xt    = (u16*)d_ws;
    u16*   wimg  = (u16*)((char*)d_ws + WIMG_OFF);
    float* stats = (float*)((char*)d_ws + STATS_OFF);
    float* part  = (float*)((char*)d_ws + PART_OFF);

    hipMemsetAsync(stats, 0, 1024, stream);
    k_prep<<<dim3(2048 + 72), dim3(256), 0, stream>>>(x, xt, w, wimg);
    if (ws_size >= WS_NEED) {
        // K-split x2: half0 -> d_out, half1 -> part; sum+stats; normalize
        k_dcn<<<dim3(1024), dim3(256), 0, stream>>>(xt, wimg, offp, mskp,
                                                    outp, part, stats, NSTEP / 2);
        k_sumsq<<<dim3(2048), dim3(256), 0, stream>>>(outp, part, outp, stats);
    } else {
        k_dcn<<<dim3(512), dim3(256), 0, stream>>>(xt, wimg, offp, mskp,
                                                   outp, part, stats, NSTEP);
        k_sumsq1<<<dim3(2048), dim3(256), 0, stream>>>(outp, stats);
    }
    k_gn<<<dim3(2048), dim3(256), 0, stream>>>(outp, stats, gamma, beta);
}

// Round 7
// 185.826 us; speedup vs baseline: 2.6283x; 2.6283x over previous
//
#include <hip/hip_runtime.h>
#include <stdint.h>

// DyDCNv2 + GroupNorm(16). B=8, C=O=256, H=W=64, fp32 in/out.
// Implicit GEMM M=32768,N=256,K=2304 bf16 MFMA.
// R7: R5 core (64pos x 256n, grid 512 XCD-affine, lgkm-only barriers,
// register weight dbuf) + distance-2 gather prefetch (2 g-sets, ~1.5 steps of
// load->use slack) + packw spread to 288 blocks (1 item/thread, no tail).
// NOTE: (256,2) only — (256,4) caps regs at 128 and spills (R6: 1 GB scratch).

#define B_ 8
#define C_ 256
#define O_ 256
#define H_ 64
#define W_ 64
#define HW_ 4096
#define KTOT 2304
#define GROUPS_ 16
#define EPS_ 1e-5f
#define NSTEP 36           // 36 steps x 64 ch
#define VROW 72            // lds_v row stride in u16 (64 data + 8 pad)

typedef float  f32x4  __attribute__((ext_vector_type(4)));
typedef short  short8 __attribute__((ext_vector_type(8)));
typedef unsigned int   u32;
typedef unsigned short u16;

// workspace layout (bytes)
#define XT_BYTES   (B_*HW_*C_*2)                // 16,777,216  xt [B][HW][C] bf16
#define WIMG_OFF   XT_BYTES
#define WIMG_BYTES (72*16*64*16)                // 1,179,648  frag-packed bf16 weights
#define STATS_OFF  (WIMG_OFF + WIMG_BYTES)      // 256 floats

__device__ __forceinline__ u32 bf16r(float f) {  // RNE f32->bf16
    u32 u = __float_as_uint(f);
    return (u + 0x7fffu + ((u >> 16) & 1u)) >> 16;
}
__device__ __forceinline__ u32 pack_bf16x2(float lo, float hi) {
    return bf16r(lo) | (bf16r(hi) << 16);
}
// 1-op pack: D = [hi.b3 hi.b2 lo.b3 lo.b2] (truncation round; errors cancel over K)
__device__ __forceinline__ u32 pack_perm(float lo, float hi) {
    return __builtin_amdgcn_perm(__float_as_uint(hi), __float_as_uint(lo), 0x07060302u);
}
__device__ __forceinline__ float bflo(u32 u) { return __uint_as_float(u << 16); }
// free: high bf16 in place; low 16 bits carry the sibling bf16 (rel err < 2^-8)
__device__ __forceinline__ float bfhi_f(u32 u) { return __uint_as_float(u); }

// barrier waiting only on LDS ops: register-destined global loads stay in flight
__device__ __forceinline__ void barrier_lds() {
    asm volatile("s_waitcnt lgkmcnt(0)\n\ts_barrier" ::: "memory");
}

// ---------------------------------------------------------------- prep: transpose + packw
__global__ void k_prep(const float* __restrict__ x, u16* __restrict__ xt,
                       const float* __restrict__ w, u16* __restrict__ wimg) {
    const int bid = blockIdx.x;
    const int tid = threadIdx.x;
    if (bid < 2048) {
        // transpose x[B][C][HW] -> xt[B][HW][C] bf16, 64c x 64p tiles
        __shared__ float tile[64][65];
        const int b = bid >> 8, ct = (bid >> 6) & 3, pt = bid & 63;
#pragma unroll
        for (int pass = 0; pass < 4; ++pass) {
            const int r  = (tid >> 4) + pass * 16;
            const int pq = tid & 15;
            const f32x4 v = *(const f32x4*)&x[(((size_t)(b * C_ + ct * 64 + r)) << 12)
                                              + pt * 64 + pq * 4];
            tile[r][pq * 4 + 0] = v.x;
            tile[r][pq * 4 + 1] = v.y;
            tile[r][pq * 4 + 2] = v.z;
            tile[r][pq * 4 + 3] = v.w;
        }
        __syncthreads();
        const int pr = tid >> 2, cg = tid & 3;    // 64 p-rows x 4 groups of 16 ch
        u32 o[8];
#pragma unroll
        for (int j = 0; j < 8; ++j)
            o[j] = pack_bf16x2(tile[cg * 16 + 2 * j][pr], tile[cg * 16 + 2 * j + 1][pr]);
        u16* dst = &xt[(((size_t)b << 12) + pt * 64 + pr) * 256 + ct * 64 + cg * 16];
        *(uint4*)dst       = *(uint4*)&o[0];
        *(uint4*)(dst + 8) = *(uint4*)&o[4];
    } else {
        // pack weights: 1 item/thread over 288 blocks (no serial tail).
        // wimg[sub][frag][lane][8], sub=k*8+ctile; lane(col,quad) holds
        // W[n=frag*16+col][c0+quad*8+j][k]
        const int item = (bid - 2048) * 256 + tid;    // 0..73727
        if (item < 72 * 1024) {
            const int sub = item >> 10;
            const int idx = item & 1023;              // frag*64 + lane
            const int k  = sub >> 3;
            const int c0 = (sub & 7) * 32;
            const int lane = idx & 63;
            const int frag = idx >> 6;
            const int col = lane & 15, quad = lane >> 4;
            const int n = frag * 16 + col;
            const float* src = w + (size_t)n * KTOT + (size_t)(c0 + quad * 8) * 9 + k;
            u32 o[4];
#pragma unroll
            for (int j = 0; j < 4; ++j)
                o[j] = pack_bf16x2(src[(size_t)(2 * j) * 9], src[(size_t)(2 * j + 1) * 9]);
            *(uint4*)&wimg[((size_t)sub * 1024 + idx) * 8] = *(uint4*)o;
        }
    }
}

// ---------------------------------------------------------------- k_dcn helpers
__device__ __forceinline__ void issue_gather(const u16* __restrict__ cb,
                                             const float* __restrict__ mwp,
                                             const int* __restrict__ mip,
                                             int gpos, uint4 g[8], f32x4& mw) {
    mw = *(const f32x4*)&mwp[gpos * 4];
    const int4 ix = *(const int4*)&mip[gpos * 4];
    const u16* p0 = cb + ix.x;
    const u16* p1 = cb + ix.y;
    const u16* p2 = cb + ix.z;
    const u16* p3 = cb + ix.w;
    g[0] = *(const uint4*)p0; g[1] = *(const uint4*)(p0 + 8);
    g[2] = *(const uint4*)p1; g[3] = *(const uint4*)(p1 + 8);
    g[4] = *(const uint4*)p2; g[5] = *(const uint4*)(p2 + 8);
    g[6] = *(const uint4*)p3; g[7] = *(const uint4*)(p3 + 8);
}

__device__ __forceinline__ void interp_store(const uint4 g[8], f32x4 mw, u16* dst) {
    float s[16];
#pragma unroll
    for (int i = 0; i < 16; ++i) s[i] = 0.f;
    const float ww[4] = {mw.x, mw.y, mw.z, mw.w};
#pragma unroll
    for (int cr = 0; cr < 4; ++cr) {
        const float wg = ww[cr];
        const uint4 a = g[2 * cr], bq = g[2 * cr + 1];
        s[0]  += wg * bflo(a.x);  s[1]  += wg * bfhi_f(a.x);
        s[2]  += wg * bflo(a.y);  s[3]  += wg * bfhi_f(a.y);
        s[4]  += wg * bflo(a.z);  s[5]  += wg * bfhi_f(a.z);
        s[6]  += wg * bflo(a.w);  s[7]  += wg * bfhi_f(a.w);
        s[8]  += wg * bflo(bq.x); s[9]  += wg * bfhi_f(bq.x);
        s[10] += wg * bflo(bq.y); s[11] += wg * bfhi_f(bq.y);
        s[12] += wg * bflo(bq.z); s[13] += wg * bfhi_f(bq.z);
        s[14] += wg * bflo(bq.w); s[15] += wg * bfhi_f(bq.w);
    }
    uint4 pk0, pk1;
    pk0.x = pack_perm(s[0], s[1]);   pk0.y = pack_perm(s[2], s[3]);
    pk0.z = pack_perm(s[4], s[5]);   pk0.w = pack_perm(s[6], s[7]);
    pk1.x = pack_perm(s[8], s[9]);   pk1.y = pack_perm(s[10], s[11]);
    pk1.z = pack_perm(s[12], s[13]); pk1.w = pack_perm(s[14], s[15]);
    *(uint4*)dst = pk0;
    *(uint4*)(dst + 8) = pk1;
}

__device__ __forceinline__ void load_wfrags(const u16* __restrict__ wimg, int s,
                                            int wid, int lane, short8 bf[8]) {
#pragma unroll
    for (int kc = 0; kc < 2; ++kc)
#pragma unroll
        for (int ni = 0; ni < 4; ++ni)
            bf[kc * 4 + ni] = *(const short8*)
                &wimg[(((size_t)(2 * s + kc) * 16 + wid * 4 + ni) * 64 + lane) * 8];
}

// ---------------------------------------------------------------- main fused DCN GEMM
// grid 512: b = gid%8 (XCD-affine), m-tile 64 pos. 256 thr = 4 waves;
// wave w: 64 pos x n in [w*64, +64). Step = 64 channels (2 MFMA sub-steps).
__launch_bounds__(256, 2)
__global__ void k_dcn(const u16* __restrict__ xt, const u16* __restrict__ wimg,
                      const float* __restrict__ offp, const float* __restrict__ mskp,
                      float* __restrict__ out, float* __restrict__ stats) {
    __shared__ __align__(16) float meta_w[9 * 64 * 4];   // 9216 B
    __shared__ __align__(16) int   meta_i[9 * 64 * 4];   // 9216 B
    __shared__ __align__(16) u16   lds_v[2][64 * VROW];  // 18432 B dbuf val tile

    const int tid = threadIdx.x;
    const int gid = blockIdx.x;
    const int b   = gid & 7;            // XCD-affine
    const int m0  = (gid >> 3) * 64;
    const int lane = tid & 63, wid = tid >> 6;
    const int col = lane & 15, quad = lane >> 4;
    const int gpos = tid >> 2, oct = tid & 3;   // gather role: (pos 0..63, 16-ch oct)

    const u16* xtb = xt + ((size_t)b << 20);

    // ---- bilinear meta for 64 positions x 9 kernel points, once
    for (int it = tid; it < 576; it += 256) {
        const int pos = it & 63, k = it >> 6;
        const int pg = m0 + pos;
        const int hh = pg >> 6, wwi = pg & 63;
        const float dy = offp[((size_t)(b * 18 + 2 * k) << 12) + pg];
        const float dx = offp[((size_t)(b * 18 + 2 * k + 1) << 12) + pg];
        const float mv = mskp[((size_t)(b * 9 + k) << 12) + pg];
        const float ys = (float)(hh + (k / 3) - 1) + dy;
        const float xs = (float)(wwi + (k % 3) - 1) + dx;
        const float y0f = floorf(ys), x0f = floorf(xs);
        const int y0 = (int)y0f, x0 = (int)x0f;
        const float wy1 = ys - y0f, wx1 = xs - x0f;
        const float wy0 = 1.f - wy1, wx0 = 1.f - wx1;
        const int y1 = y0 + 1, x1 = x0 + 1;
        const float vy0 = (y0 >= 0 && y0 < H_) ? 1.f : 0.f;
        const float vy1 = (y1 >= 0 && y1 < H_) ? 1.f : 0.f;
        const float vx0 = (x0 >= 0 && x0 < W_) ? 1.f : 0.f;
        const float vx1 = (x1 >= 0 && x1 < W_) ? 1.f : 0.f;
        const int y0c = min(max(y0, 0), H_ - 1), y1c = min(max(y1, 0), H_ - 1);
        const int x0c = min(max(x0, 0), W_ - 1), x1c = min(max(x1, 0), W_ - 1);
        meta_w[it * 4 + 0] = mv * wy0 * wx0 * vy0 * vx0;
        meta_w[it * 4 + 1] = mv * wy0 * wx1 * vy0 * vx1;
        meta_w[it * 4 + 2] = mv * wy1 * wx0 * vy1 * vx0;
        meta_w[it * 4 + 3] = mv * wy1 * wx1 * vy1 * vx1;
        meta_i[it * 4 + 0] = (y0c * W_ + x0c) << 8;   // row offsets in u16 units
        meta_i[it * 4 + 1] = (y0c * W_ + x1c) << 8;
        meta_i[it * 4 + 2] = (y1c * W_ + x0c) << 8;
        meta_i[it * 4 + 3] = (y1c * W_ + x1c) << 8;
    }
    __syncthreads();

    // ---- prologue: stage step 0 into buf0; issue step-1 gathers; wfrags step 0
    uint4 g2[2][8]; f32x4 mw2[2]; short8 bf_cur[8], bf_nxt[8];
    issue_gather(xtb + 0 + oct * 16, &meta_w[0], &meta_i[0], gpos, g2[0], mw2[0]);
    load_wfrags(wimg, 0, wid, lane, bf_cur);
    interp_store(g2[0], mw2[0], &lds_v[0][gpos * VROW + oct * 16]);   // step 0 -> buf0
    issue_gather(xtb + 64 + oct * 16, &meta_w[0], &meta_i[0], gpos, g2[1], mw2[1]); // s=1: k=0,c0=64
    __syncthreads();

    f32x4 acc[4][4];
#pragma unroll
    for (int i = 0; i < 4; ++i)
#pragma unroll
        for (int j = 0; j < 4; ++j) acc[i][j] = (f32x4){0.f, 0.f, 0.f, 0.f};

#pragma unroll 2
    for (int s = 0; s < NSTEP; ++s) {
        const int p = s & 1;

        // 1. weight frags for s+1 (distance-1 register prefetch; L2-resident)
        if (s + 1 < NSTEP) load_wfrags(wimg, s + 1, wid, lane, bf_nxt);

        // 2. gathers for s+2 into the set freed by last step's interp
        if (s + 2 < NSTEP) {
            const int sn = s + 2;
            const int kn = sn >> 2, c0n = (sn & 3) * 64;
            issue_gather(xtb + c0n + oct * 16, &meta_w[kn * 256], &meta_i[kn * 256],
                         gpos, g2[p], mw2[p]);
        }

        // 3. compute current step: 2 sub-steps of 32 ch
#pragma unroll
        for (int kc = 0; kc < 2; ++kc) {
            short8 af[4];
#pragma unroll
            for (int mi = 0; mi < 4; ++mi)
                af[mi] = *(const short8*)
                    &lds_v[p][(mi * 16 + col) * VROW + kc * 32 + quad * 8];
#pragma unroll
            for (int mi = 0; mi < 4; ++mi)
#pragma unroll
                for (int ni = 0; ni < 4; ++ni)
                    acc[mi][ni] = __builtin_amdgcn_mfma_f32_16x16x32_bf16(
                        af[mi], bf_cur[kc * 4 + ni], acc[mi][ni], 0, 0, 0);
        }

        // 4. interp s+1 (gathers issued at s-1, ~1.5 steps ago) into other buffer
        if (s + 1 < NSTEP)
            interp_store(g2[1 - p], mw2[1 - p], &lds_v[1 - p][gpos * VROW + oct * 16]);

        // 5. LDS-only barrier: gather/weight prefetches stay in flight
        barrier_lds();

#pragma unroll
        for (int j = 0; j < 8; ++j) bf_cur[j] = bf_nxt[j];
    }

    // ---- epilogue: store pre-GN output. D: row(pos)=quad*4+r, col(o)=lane&15.
#pragma unroll
    for (int mi = 0; mi < 4; ++mi)
#pragma unroll
        for (int ni = 0; ni < 4; ++ni) {
            const int o  = wid * 64 + ni * 16 + col;
            const int pg = m0 + mi * 16 + quad * 4;
            *(f32x4*)(out + (((size_t)b * O_ + o) << 12) + pg) = acc[mi][ni];
        }

    // ---- GN stats: (wave, ni) = one 16-channel group x 64 positions
#pragma unroll
    for (int ni = 0; ni < 4; ++ni) {
        float s = 0.f, s2 = 0.f;
#pragma unroll
        for (int mi = 0; mi < 4; ++mi) {
            f32x4 v = acc[mi][ni];
            s  += v.x + v.y + v.z + v.w;
            s2 += v.x * v.x + v.y * v.y + v.z * v.z + v.w * v.w;
        }
#pragma unroll
        for (int d = 32; d > 0; d >>= 1) {
            s  += __shfl_xor(s, d, 64);
            s2 += __shfl_xor(s2, d, 64);
        }
        if (lane == 0) {
            const int gI = wid * 4 + ni;
            atomicAdd(&stats[b * GROUPS_ + gI], s);
            atomicAdd(&stats[128 + b * GROUPS_ + gI], s2);
        }
    }
}

// ---------------------------------------------------------------- apply GN in place
__global__ void k_gn(float* __restrict__ out, const float* __restrict__ stats,
                     const float* __restrict__ gamma, const float* __restrict__ beta) {
    const int blk = blockIdx.x;            // b*256 + o
    const int b = blk >> 8, o = blk & 255;
    const int gI = b * GROUPS_ + (o >> 4);
    const float n = 65536.f;               // (C/G)*H*W
    const float mean = stats[gI] / n;
    const float var  = stats[128 + gI] / n - mean * mean;
    const float inv  = rsqrtf(fmaxf(var, 0.f) + EPS_);
    const float scale = inv * gamma[o];
    const float shift = beta[o] - mean * scale;
    f32x4* p = (f32x4*)(out + ((size_t)blk << 12));
    const int t = threadIdx.x;
#pragma unroll
    for (int i = 0; i < 4; ++i) {
        f32x4 v = p[t + i * 256];
        p[t + i * 256] = v * scale + shift;
    }
}

extern "C" void kernel_launch(void* const* d_in, const int* in_sizes, int n_in,
                              void* d_out, int out_size, void* d_ws, size_t ws_size,
                              hipStream_t stream) {
    const float* x     = (const float*)d_in[0];
    const float* offp  = (const float*)d_in[1];
    const float* mskp  = (const float*)d_in[2];
    const float* w     = (const float*)d_in[3];
    const float* gamma = (const float*)d_in[4];
    const float* beta  = (const float*)d_in[5];
    float* outp = (float*)d_out;

    u16*   xt    = (u16*)d_ws;
    u16*   wimg  = (u16*)((char*)d_ws + WIMG_OFF);
    float* stats = (float*)((char*)d_ws + STATS_OFF);

    hipMemsetAsync(stats, 0, 1024, stream);
    k_prep<<<dim3(2048 + 288), dim3(256), 0, stream>>>(x, xt, w, wimg);
    k_dcn<<<dim3(512), dim3(256), 0, stream>>>(xt, wimg, offp, mskp, outp, stats);
    k_gn<<<dim3(2048), dim3(256), 0, stream>>>(outp, stats, gamma, beta);
}